// Round 5
// baseline (161.401 us; speedup 1.0000x reference)
//
#include <hip/hip_runtime.h>
#include <cstdint>
#include <cstddef>

#define BSZ 16
#define LQ  512
#define HIDDIM 768
#define NH  12
#define HD  64
#define R2V 16
#define NTOT 1536   // fused N: K cols [0,768) | V cols [768,1536)
#define MTOT 8192   // BSZ*LQ

typedef __bf16 bf16x8 __attribute__((ext_vector_type(8)));
typedef float  f32x4  __attribute__((ext_vector_type(4)));

__device__ inline unsigned short f2bf(float x) {
    union { float f; unsigned u; } c; c.f = x;
    unsigned r = c.u + 0x7fffu + ((c.u >> 16) & 1u);   // RNE (no NaN here)
    return (unsigned short)(r >> 16);
}
__device__ inline float bfl(unsigned u) { return __uint_as_float(u << 16); }
__device__ inline float bfh(unsigned u) { return __uint_as_float(u & 0xffff0000u); }

// pack (x,y) -> uint with bf16(x) in low half, bf16(y) in high half (RNE)
__device__ inline unsigned pk2bf(float x, float y) {
#if __has_builtin(__builtin_amdgcn_cvt_pk_bf16_f32)
    typedef __bf16 bf16x2 __attribute__((ext_vector_type(2)));
    union { bf16x2 v; unsigned u; } c;
    c.v = __builtin_amdgcn_cvt_pk_bf16_f32(x, y);
    return c.u;
#else
    return (unsigned)f2bf(x) | ((unsigned)f2bf(y) << 16);
#endif
}

// ---------------------------------------------------------------------------
// Kernel 1: fused fp32->bf16 + MFMA GEMM -> bf16 outputs.
// C[m,n] = relu(sum_k A[m,k]*W[n,k] + bias[n]); A=hs fp32, W=Kw|Vw fp32.
// 128x128 tile, BK=32, 256 threads = 4 waves, 16x16x32 bf16 MFMA.
// Staging: fp32 global->VGPR (dwordx4), packed cvt->bf16, ds_write_b128 into
// double-buffered LDS; ONE barrier per K-iter (loads for t+1 issued before the
// MFMA phase of t hides latency; convert+write lands after).
// Swapped-operand MFMA -> C^T layout -> ushort4 stores.
// ---------------------------------------------------------------------------
#define TBM 128
#define TBN 128
#define TBK 32
#define KITERS (HIDDIM / TBK)   // 24

__global__ __launch_bounds__(256, 3) void gemm_fused(
    const float* __restrict__ hs,                       // 8192 x 768 fp32
    const float* __restrict__ Kw, const float* __restrict__ Vw,  // 768 x 768
    const float* __restrict__ Kb, const float* __restrict__ Vb,  // 768
    unsigned short* __restrict__ K1b, unsigned short* __restrict__ V1b)
{
    __shared__ unsigned short As[2][TBM * TBK];  // 2 x 8 KB
    __shared__ unsigned short Bs[2][TBN * TBK];  // 2 x 8 KB

    const int n0   = blockIdx.x * TBN;
    const int m0   = blockIdx.y * TBM;
    const int tid  = threadIdx.x;
    const int wid  = tid >> 6;
    const int lane = tid & 63;
    const int wm   = (wid & 1) * 64;
    const int wn   = (wid >> 1) * 64;

    const bool isK = (n0 < HIDDIM);
    const float* __restrict__ Wsrc = isK ? Kw : Vw;
    const float* __restrict__ bias = isK ? Kb : Vb;
    const int ncol0 = isK ? n0 : (n0 - HIDDIM);

    f32x4 acc[4][4] = {};   // lane holds m=lane&15, n-quad=(lane>>4)*4 (C^T)

    // staging: wave wid covers rows [wid*32, wid*32+32) of both tiles.
    // lane -> row r0+(lane>>1), k-half kh=(lane&1)*16 (16 fp32 = 4 float4).
    const int r0 = wid * 32;
    const int rA = r0 + (lane >> 1);
    const int kh = (lane & 1) * 16;

    const float* Aptr = hs   + (size_t)(m0 + rA) * HIDDIM + kh;
    const float* Bptr = Wsrc + (size_t)(ncol0 + rA) * HIDDIM + kh;

    uint4* AsD = (uint4*)&As[0][rA * TBK + kh];   // [buf] indexed via +1024B units
    uint4* BsD = (uint4*)&Bs[0][rA * TBK + kh];
    const int bufStride16 = (TBM * TBK) / 8;      // uint4 elements per buffer

    float4 ar0, ar1, ar2, ar3, br0, br1, br2, br3;

#define LOADREGS(kof)                                     \
    do {                                                  \
        ar0 = *(const float4*)(Aptr + (kof));             \
        ar1 = *(const float4*)(Aptr + (kof) + 4);         \
        ar2 = *(const float4*)(Aptr + (kof) + 8);         \
        ar3 = *(const float4*)(Aptr + (kof) + 12);        \
        br0 = *(const float4*)(Bptr + (kof));             \
        br1 = *(const float4*)(Bptr + (kof) + 4);         \
        br2 = *(const float4*)(Bptr + (kof) + 8);         \
        br3 = *(const float4*)(Bptr + (kof) + 12);        \
    } while (0)

#define CVTSTORE(buf)                                                         \
    do {                                                                      \
        uint4 p;                                                              \
        p.x = pk2bf(ar0.x, ar0.y); p.y = pk2bf(ar0.z, ar0.w);                 \
        p.z = pk2bf(ar1.x, ar1.y); p.w = pk2bf(ar1.z, ar1.w);                 \
        AsD[(buf) * bufStride16] = p;                                         \
        p.x = pk2bf(ar2.x, ar2.y); p.y = pk2bf(ar2.z, ar2.w);                 \
        p.z = pk2bf(ar3.x, ar3.y); p.w = pk2bf(ar3.z, ar3.w);                 \
        AsD[(buf) * bufStride16 + 1] = p;                                     \
        p.x = pk2bf(br0.x, br0.y); p.y = pk2bf(br0.z, br0.w);                 \
        p.z = pk2bf(br1.x, br1.y); p.w = pk2bf(br1.z, br1.w);                 \
        BsD[(buf) * bufStride16] = p;                                         \
        p.x = pk2bf(br2.x, br2.y); p.y = pk2bf(br2.z, br2.w);                 \
        p.z = pk2bf(br3.x, br3.y); p.w = pk2bf(br3.z, br3.w);                 \
        BsD[(buf) * bufStride16 + 1] = p;                                     \
    } while (0)

    const int fm = lane & 15;
    const int fk = (lane >> 4) * 8;

    LOADREGS(0);
    CVTSTORE(0);    // prologue: tile 0 -> buf 0

    for (int it = 0; it < KITERS; ++it) {
        __syncthreads();   // buf[it&1] fully written; prior reads of other buf done
        const int cb = it & 1;
        if (it + 1 < KITERS) LOADREGS((it + 1) * TBK);

        bf16x8 af[4], bfr[4];
        #pragma unroll
        for (int mi = 0; mi < 4; ++mi)
            af[mi] = *reinterpret_cast<const bf16x8*>(&As[cb][(wm + mi * 16 + fm) * TBK + fk]);
        #pragma unroll
        for (int ni = 0; ni < 4; ++ni)
            bfr[ni] = *reinterpret_cast<const bf16x8*>(&Bs[cb][(wn + ni * 16 + fm) * TBK + fk]);
        #pragma unroll
        for (int mi = 0; mi < 4; ++mi)
            #pragma unroll
            for (int ni = 0; ni < 4; ++ni)
                acc[mi][ni] = __builtin_amdgcn_mfma_f32_16x16x32_bf16(
                    bfr[ni], af[mi], acc[mi][ni], 0, 0, 0);   // swapped: C^T

        if (it + 1 < KITERS) CVTSTORE(cb ^ 1);
    }
#undef LOADREGS
#undef CVTSTORE

    // epilogue: lane holds m = lane&15, n = (lane>>4)*4 + r (4 consecutive)
    unsigned short* __restrict__ dst = isK ? K1b : V1b;
    const int mloc = lane & 15;
    const int nq   = (lane >> 4) * 4;

    #pragma unroll
    for (int mi = 0; mi < 4; ++mi) {
        const int mg = m0 + wm + mi * 16 + mloc;
        #pragma unroll
        for (int ni = 0; ni < 4; ++ni) {
            const int col = ncol0 + wn + ni * 16 + nq;   // 0..767
            float4 bv = *(const float4*)(bias + col);
            f32x4 a = acc[mi][ni];
            ushort4 o;
            o.x = f2bf(fmaxf(a[0] + bv.x, 0.f));
            o.y = f2bf(fmaxf(a[1] + bv.y, 0.f));
            o.z = f2bf(fmaxf(a[2] + bv.z, 0.f));
            o.w = f2bf(fmaxf(a[3] + bv.w, 0.f));
            *(ushort4*)(dst + (size_t)mg * HIDDIM + col) = o;
        }
    }
}

// ---------------------------------------------------------------------------
// Kernel 2: fused per (b,h): scores -> softmax(+exp(-m)) -> events -> scans
// -> idx (LDS) -> gather from V1b -> out.  512 threads = 8 waves; 192 blocks.
// Gather chunked 4-deep (unroll 1 on chunk loop) to cap VGPR pressure.
// ---------------------------------------------------------------------------
#define SINF (1 << 30)
#define IXP 17   // idxs row stride (pad 16->17)

__global__ __launch_bounds__(512) void scan_gather(
    const unsigned short* __restrict__ K1b,
    const unsigned short* __restrict__ V1b,
    const float* __restrict__ rh,
    const float* __restrict__ bw,
    float* __restrict__ out)
{
    const int bh   = blockIdx.x;       // 0..191
    const int b    = bh / NH;
    const int h    = bh % NH;
    const int l    = threadIdx.x;      // 0..511
    const int lane = l & 63;
    const int wid  = l >> 6;

    __shared__ float wredA[8];
    __shared__ float wredB[8];
    __shared__ int   wp0[8];
    __shared__ int   wp1[8];
    __shared__ int   wp2[8];
    __shared__ int   ev[LQ];
    __shared__ int   col0[LQ];
    __shared__ int   col1[LQ];
    __shared__ int   E[LQ];
    __shared__ int   idxs[LQ * IXP];   // ~34.8 KB
    __shared__ float wsm[R2V];

    if (l < R2V) wsm[l] = bw[h * R2V + l];

    // ---- 1. score: dot64(bf16 K1 row, fp32 reading_head) ----
    const unsigned short* krow = K1b + ((size_t)(b * LQ + l)) * HIDDIM + h * HD;
    const float* rrow = rh + h * HD;
    float s = 0.f;
    #pragma unroll
    for (int c8 = 0; c8 < 8; ++c8) {
        uint4 kv = *(const uint4*)(krow + c8 * 8);
        float4 ra = *(const float4*)(rrow + c8 * 8);
        float4 rb = *(const float4*)(rrow + c8 * 8 + 4);
        s += bfl(kv.x) * ra.x + bfh(kv.x) * ra.y
           + bfl(kv.y) * ra.z + bfh(kv.y) * ra.w
           + bfl(kv.z) * rb.x + bfh(kv.z) * rb.y
           + bfl(kv.w) * rb.z + bfh(kv.w) * rb.w;
    }

    // ---- 2. max reduce ----
    float mx = s;
    #pragma unroll
    for (int off = 32; off > 0; off >>= 1) mx = fmaxf(mx, __shfl_xor(mx, off));
    if (lane == 0) wredA[wid] = mx;
    __syncthreads();
    float m = wredA[0];
    #pragma unroll
    for (int i = 1; i < 8; ++i) m = fmaxf(m, wredA[i]);

    // ---- 3. sum reduce ----
    const float e = expf(s - m);
    float sm = e;
    #pragma unroll
    for (int off = 32; off > 0; off >>= 1) sm += __shfl_xor(sm, off);
    if (lane == 0) wredB[wid] = sm;
    __syncthreads();
    float ssum = 0.f;
    #pragma unroll
    for (int i = 0; i < 8; ++i) ssum += wredB[i];

    const float p = e / ssum + expf(-m);
    const int event = (p > (1.5f / 512.0f)) ? 1 : 0;
    ev[l] = event;

    // ---- 4. col0: inclusive max-scan of (event ? l : -1) ----
    int v = event ? l : -1;
    #pragma unroll
    for (int off = 1; off < 64; off <<= 1) {
        int u = __shfl_up(v, off);
        if (lane >= off) v = (u > v) ? u : v;
    }
    if (lane == 63) wp0[wid] = v;
    __syncthreads();                     // ev + wp0 visible
    int pfx = -1;
    for (int i = 0; i < wid; ++i) pfx = (wp0[i] > pfx) ? wp0[i] : pfx;
    v = (pfx > v) ? pfx : v;
    col0[l] = (v >= 0) ? v : l;

    // ---- 5. col1: suffix min-scan of (ev[(l+1)&511] ? l : INF) ----
    int v1 = ev[(l + 1) & (LQ - 1)] ? l : SINF;
    #pragma unroll
    for (int off = 1; off < 64; off <<= 1) {
        int u = __shfl_down(v1, off);
        if (lane < 64 - off) v1 = (u < v1) ? u : v1;
    }
    if (lane == 0) wp1[wid] = v1;
    __syncthreads();
    int sfx = SINF;
    for (int i = wid + 1; i < 8; ++i) sfx = (wp1[i] < sfx) ? wp1[i] : sfx;
    v1 = (sfx < v1) ? sfx : v1;
    col1[l] = (l == 0) ? 0 : (((v1 < SINF) ? v1 : l) + 1);

    // ---- 6. prefix count of events over steps 1..l ----
    int c = (l >= 1) ? event : 0;
    #pragma unroll
    for (int off = 1; off < 64; off <<= 1) {
        int u = __shfl_up(c, off);
        if (lane >= off) c += u;
    }
    if (lane == 63) wp2[wid] = c;
    __syncthreads();
    for (int i = 0; i < wid; ++i) c += wp2[i];

    // ---- 7. event-time list ----
    if (l >= 1 && event) E[c - 1] = l;
    __syncthreads();                     // E, col0, col1 ready

    // ---- 8. idx registers -> LDS ----
    int* op = &idxs[l * IXP];
    #pragma unroll
    for (int j = 0; j < 8; ++j) {
        const int k = c - 1 - j;
        int f = 0, bb = 0;
        if (k >= 0) {
            const int t = E[k];          // t >= 1
            f  = col0[t - 1];
            bb = col1[t - 1];
        }
        op[2 * j]     = min(max(f, 0), LQ - 1);
        op[2 * j + 1] = min(max(bb, 0), LQ - 1);
    }
    __syncthreads();                     // idxs + wsm ready

    // ---- 9. gather: 8 lanes per l (dsl covers 8 d's), 8 rounds, 4-chunked ----
    const int dsl = lane & 7;
    const size_t vbase = (size_t)b * LQ * HIDDIM + h * HD + dsl * 8;

    for (int round = 0; round < 8; ++round) {
        const int lg = round * 64 + wid * 8 + (lane >> 3);
        const int* ip = &idxs[lg * IXP];
        float a0 = 0.f, a1 = 0.f, a2 = 0.f, a3 = 0.f;
        float a4 = 0.f, a5 = 0.f, a6 = 0.f, a7 = 0.f;
        #pragma unroll 1
        for (int rc = 0; rc < R2V; rc += 4) {
            const int i0 = ip[rc], i1 = ip[rc + 1], i2 = ip[rc + 2], i3 = ip[rc + 3];
            uint4 v0 = *(const uint4*)(V1b + vbase + (size_t)i0 * HIDDIM);
            uint4 vA = *(const uint4*)(V1b + vbase + (size_t)i1 * HIDDIM);
            uint4 vB = *(const uint4*)(V1b + vbase + (size_t)i2 * HIDDIM);
            uint4 vC = *(const uint4*)(V1b + vbase + (size_t)i3 * HIDDIM);
            const float w0 = wsm[rc], w1 = wsm[rc + 1], w2 = wsm[rc + 2], w3 = wsm[rc + 3];
            a0 += w0 * bfl(v0.x); a1 += w0 * bfh(v0.x);
            a2 += w0 * bfl(v0.y); a3 += w0 * bfh(v0.y);
            a4 += w0 * bfl(v0.z); a5 += w0 * bfh(v0.z);
            a6 += w0 * bfl(v0.w); a7 += w0 * bfh(v0.w);
            a0 += w1 * bfl(vA.x); a1 += w1 * bfh(vA.x);
            a2 += w1 * bfl(vA.y); a3 += w1 * bfh(vA.y);
            a4 += w1 * bfl(vA.z); a5 += w1 * bfh(vA.z);
            a6 += w1 * bfl(vA.w); a7 += w1 * bfh(vA.w);
            a0 += w2 * bfl(vB.x); a1 += w2 * bfh(vB.x);
            a2 += w2 * bfl(vB.y); a3 += w2 * bfh(vB.y);
            a4 += w2 * bfl(vB.z); a5 += w2 * bfh(vB.z);
            a6 += w2 * bfl(vB.w); a7 += w2 * bfh(vB.w);
            a0 += w3 * bfl(vC.x); a1 += w3 * bfh(vC.x);
            a2 += w3 * bfl(vC.y); a3 += w3 * bfh(vC.y);
            a4 += w3 * bfl(vC.z); a5 += w3 * bfh(vC.z);
            a6 += w3 * bfl(vC.w); a7 += w3 * bfh(vC.w);
        }
        float* po = out + ((size_t)(b * LQ + lg) * NH + h) * HD + dsl * 8;
        *(float4*)po       = make_float4(a0, a1, a2, a3);
        *((float4*)po + 1) = make_float4(a4, a5, a6, a7);
    }
}

// ---------------------------------------------------------------------------
extern "C" void kernel_launch(void* const* d_in, const int* in_sizes, int n_in,
                              void* d_out, int out_size, void* d_ws, size_t ws_size,
                              hipStream_t stream)
{
    (void)in_sizes; (void)n_in; (void)out_size; (void)ws_size;

    const float* hs = (const float*)d_in[0];
    const float* Kw = (const float*)d_in[1];
    const float* Kb = (const float*)d_in[2];
    const float* Vw = (const float*)d_in[3];
    const float* Vb = (const float*)d_in[4];
    const float* rh = (const float*)d_in[5];
    const float* bw = (const float*)d_in[6];
    float* out = (float*)d_out;

    // ws layout (bytes):
    //   K1b  bf16 8192*768  @ 0         (12.58 MB)
    //   V1b  bf16 8192*768  @ 12582912  (12.58 MB)
    char* ws = (char*)d_ws;
    unsigned short* K1b = (unsigned short*)(ws);
    unsigned short* V1b = (unsigned short*)(ws + 12582912);

    dim3 g1(NTOT / TBN, MTOT / TBM);   // 12 x 64
    gemm_fused<<<g1, 256, 0, stream>>>(hs, Kw, Vw, Kb, Vb, K1b, V1b);

    scan_gather<<<BSZ * NH, LQ, 0, stream>>>(K1b, V1b, rh, bw, out);
}